// Round 13
// baseline (101.664 us; speedup 1.0000x reference)
//
#include <hip/hip_runtime.h>
#include <math.h>

// force = MLP(|dr|) is piecewise-linear in the scalar edge length -> dense
// fp32 table of force(d) parameterized by u = d/(1+d) (data-independent).
//
// Round-13: producer writes compactly, consumer reads densely -- with FEW
// buckets so both hold at once:
//  memset: zero 49 bucket counters (196 B).
//  kprod (782+256 blocks x 256t): blocks <782 bin 1024 edges into 49
//      node-range buckets (RANGE_N=2048): LDS histogram (49-way, low
//      conflict), ONE global atomicAdd per (block,bucket) reserves a span
//      in the bucket's fixed region, scatter float4{dloc,dx,dy,u} as ~21-
//      entry contiguous runs. Blocks >=782 build the 4096-entry table.
//  kcons (49 blocks x 1024t): block r streams its bucket's DENSE span
//      (16/thread, deep pipeline), table-lerp, 16 KB LDS accumulate,
//      out = acc - gamma*v directly. No partials, no 4th kernel.

#define M_TAB 4096
#define INV_MTAB (1.0f / 4096.0f)
#define EPSF 1e-12f
#define RANGE_N 2048
#define RSHIFT 11
#define BCHUNK 1024
#define TPTS 16
#define CAP 32768
#define NBUCK_MAX 64

// Table builder: thread j(<128) = neuron j, TPTS grid points per task.
// All threads of the block must enter (uniform barriers).
__device__ __forceinline__ void build_table16(
    int base, int tid, const float* __restrict__ W0,
    const float* __restrict__ b0, const float* __restrict__ W1,
    const float* __restrict__ b1, const float* __restrict__ W2,
    const float* __restrict__ b2, const float* __restrict__ W3,
    const float* __restrict__ b3, float* __restrict__ table,
    float* bufA, float* bufB) {
  const int j = tid;
  if (j < 128) {
    float w = W0[j], b = b0[j];
#pragma unroll
    for (int p = 0; p < TPTS; ++p) {
      float u = (float)(base + p) * INV_MTAB;
      float dd = u / (1.f - u);
      bufA[j * TPTS + p] = fmaxf(fmaf(dd, w, b), 0.f);
    }
  }
  __syncthreads();
  float acc[TPTS];
  if (j < 128) {
    float b = b1[j];
#pragma unroll
    for (int p = 0; p < TPTS; ++p) acc[p] = b;
#pragma unroll 4
    for (int k = 0; k < 128; ++k) {
      float w = W1[k * 128 + j];
#pragma unroll
      for (int q = 0; q < 4; ++q) {
        float4 h = *(const float4*)&bufA[k * TPTS + q * 4];
        acc[q * 4 + 0] = fmaf(h.x, w, acc[q * 4 + 0]);
        acc[q * 4 + 1] = fmaf(h.y, w, acc[q * 4 + 1]);
        acc[q * 4 + 2] = fmaf(h.z, w, acc[q * 4 + 2]);
        acc[q * 4 + 3] = fmaf(h.w, w, acc[q * 4 + 3]);
      }
    }
  }
  __syncthreads();
  if (j < 128) {
#pragma unroll
    for (int p = 0; p < TPTS; ++p) bufB[j * TPTS + p] = fmaxf(acc[p], 0.f);
  }
  __syncthreads();
  if (j < 128) {
    float b = b2[j];
#pragma unroll
    for (int p = 0; p < TPTS; ++p) acc[p] = b;
#pragma unroll 4
    for (int k = 0; k < 128; ++k) {
      float w = W2[k * 128 + j];
#pragma unroll
      for (int q = 0; q < 4; ++q) {
        float4 h = *(const float4*)&bufB[k * TPTS + q * 4];
        acc[q * 4 + 0] = fmaf(h.x, w, acc[q * 4 + 0]);
        acc[q * 4 + 1] = fmaf(h.y, w, acc[q * 4 + 1]);
        acc[q * 4 + 2] = fmaf(h.z, w, acc[q * 4 + 2]);
        acc[q * 4 + 3] = fmaf(h.w, w, acc[q * 4 + 3]);
      }
    }
  }
  __syncthreads();
  if (j < 128) {
    float w3 = W3[j];
#pragma unroll
    for (int p = 0; p < TPTS; ++p)
      bufA[j * TPTS + p] = fmaxf(acc[p], 0.f) * w3;
  }
  __syncthreads();
  for (int s = 64; s > 0; s >>= 1) {
    if (j < s) {
#pragma unroll
      for (int p = 0; p < TPTS; ++p)
        bufA[j * TPTS + p] += bufA[(j + s) * TPTS + p];
    }
    __syncthreads();
  }
  if (j < TPTS) table[base + j] = bufA[j] + b3[0];
}

// kprod: blocks < NB bin their 1024-edge chunk; blocks >= NB build table.
__global__ __launch_bounds__(256) void kprod(
    const float* __restrict__ x, const int* __restrict__ src,
    const int* __restrict__ dst, const float* __restrict__ W0,
    const float* __restrict__ b0, const float* __restrict__ W1,
    const float* __restrict__ b1, const float* __restrict__ W2,
    const float* __restrict__ b2, const float* __restrict__ W3,
    const float* __restrict__ b3, float4* __restrict__ binData,
    int* __restrict__ gcnt, float* __restrict__ table, int E, int NB,
    int NBUCK) {
  __shared__ float smem[4096];  // table path bufA/bufB (16 KB)
  __shared__ int cntL[NBUCK_MAX];
  __shared__ int offL[NBUCK_MAX];
  const int tid = threadIdx.x;
  const int bid = blockIdx.x;

  if (bid < NB) {
    if (tid < NBUCK_MAX) cntL[tid] = 0;
    __syncthreads();
    const int e0 = bid * BCHUNK + tid * 4;
    int mdst[4], mrank[4];
    float2 xs[4], xt[4];
    float mdx[4], mdy[4], mu[4];
    {
      int msrc[4];
      if (e0 + 3 < E) {
        int4 a = *(const int4*)(src + e0);
        int4 c = *(const int4*)(dst + e0);
        msrc[0] = a.x; msrc[1] = a.y; msrc[2] = a.z; msrc[3] = a.w;
        mdst[0] = c.x; mdst[1] = c.y; mdst[2] = c.z; mdst[3] = c.w;
      } else {
#pragma unroll
        for (int i = 0; i < 4; ++i) {
          bool vv = (e0 + i < E);
          msrc[i] = vv ? src[e0 + i] : 0;
          mdst[i] = vv ? dst[e0 + i] : -1;
        }
      }
      // Issue all 8 gathers before dependent work (ILP).
#pragma unroll
      for (int i = 0; i < 4; ++i) {
        int si = msrc[i], di = mdst[i] < 0 ? 0 : mdst[i];
        xs[i] = ((const float2*)x)[si];
        xt[i] = ((const float2*)x)[di];
      }
    }
#pragma unroll
    for (int i = 0; i < 4; ++i) {
      mdx[i] = xt[i].x - xs[i].x;
      mdy[i] = xt[i].y - xs[i].y;
      float d = sqrtf(fmaf(mdx[i], mdx[i], mdy[i] * mdy[i]));
      mu[i] = d / (1.f + d);
    }
#pragma unroll
    for (int i = 0; i < 4; ++i)
      if (mdst[i] >= 0) mrank[i] = atomicAdd(&cntL[mdst[i] >> RSHIFT], 1);
    __syncthreads();
    if (tid < NBUCK && cntL[tid] > 0)
      offL[tid] = atomicAdd(&gcnt[tid], cntL[tid]);
    __syncthreads();
#pragma unroll
    for (int i = 0; i < 4; ++i) {
      if (mdst[i] >= 0) {
        int b = mdst[i] >> RSHIFT;
        int pos = offL[b] + mrank[i];
        if (pos < CAP)
          binData[(size_t)b * CAP + pos] =
              make_float4(__int_as_float(mdst[i] & (RANGE_N - 1)), mdx[i],
                          mdy[i], mu[i]);
      }
    }
  } else {
    build_table16((bid - NB) * TPTS, tid, W0, b0, W1, b1, W2, b2, W3, b3,
                  table, smem, smem + 2048);
  }
}

// kcons: block r streams its bucket's dense span; out = acc - gamma*v.
__global__ __launch_bounds__(1024) void kcons(
    const float4* __restrict__ binData, const int* __restrict__ gcnt,
    const float* __restrict__ table, const float* __restrict__ v,
    const float* __restrict__ gamma, float* __restrict__ out, int n_nodes) {
  __shared__ float acc[RANGE_N * 2];  // 16 KB
  const int tid = threadIdx.x;
  const int r = blockIdx.x;

  for (int i = tid; i < RANGE_N * 2; i += 1024) acc[i] = 0.f;
  __syncthreads();

  const int len = min(gcnt[r], CAP);
  const float4* span = binData + (size_t)r * CAP;
  for (int g = tid; g < len; g += 1024) {
    float4 ent = span[g];
    int dloc = __float_as_int(ent.x);
    float u = ent.w;
    float idxf = u * (float)M_TAB;
    int i0 = (int)idxf;
    if (i0 > M_TAB - 2) i0 = M_TAB - 2;
    float frac = idxf - (float)i0;
    float f0 = table[i0], f1 = table[i0 + 1];
    float f = fmaf(frac, f1 - f0, f0);
    float d = u / (1.f - u);
    float sc = f / fmaxf(d, EPSF);
    atomicAdd(&acc[dloc * 2], sc * ent.y);
    atomicAdd(&acc[dloc * 2 + 1], sc * ent.z);
  }
  __syncthreads();

  const int node0 = r * RANGE_N;
  const int cnt2 = min(RANGE_N, n_nodes - node0);
  const float gm = -gamma[0];
  float2* po = (float2*)out + node0;
  const float2* pv = (const float2*)v + node0;
  const float2* a2 = (const float2*)acc;
  for (int i = tid; i < cnt2; i += 1024) {
    float2 a = a2[i];
    float2 vv = pv[i];
    po[i] = make_float2(fmaf(gm, vv.x, a.x), fmaf(gm, vv.y, a.y));
  }
}

// ---- Fallback path (tiny d_ws only) ----
__global__ __launch_bounds__(128) void k2_table(
    const float* __restrict__ W0, const float* __restrict__ b0,
    const float* __restrict__ W1, const float* __restrict__ b1,
    const float* __restrict__ W2, const float* __restrict__ b2,
    const float* __restrict__ W3, const float* __restrict__ b3,
    float* __restrict__ table) {
  __shared__ float bufA[2048];
  __shared__ float bufB[2048];
  build_table16(blockIdx.x * TPTS, threadIdx.x, W0, b0, W1, b1, W2, b2, W3,
                b3, table, bufA, bufB);
}

__global__ __launch_bounds__(256) void k0_init(const float* __restrict__ v,
                                               const float* __restrict__ gamma,
                                               float* __restrict__ out,
                                               int n) {
  int i = blockIdx.x * blockDim.x + threadIdx.x;
  if (i < n) out[i] = -gamma[0] * v[i];
}

__global__ __launch_bounds__(256) void k3_direct(
    const float* __restrict__ x, const int* __restrict__ src,
    const int* __restrict__ dst, const float* __restrict__ table,
    float* __restrict__ out, int E) {
  int e = blockIdx.x * blockDim.x + threadIdx.x;
  if (e >= E) return;
  int s = src[e], t = dst[e];
  float2 xs = ((const float2*)x)[s];
  float2 xt = ((const float2*)x)[t];
  float dx = xt.x - xs.x, dy = xt.y - xs.y;
  float d = sqrtf(fmaf(dx, dx, dy * dy));
  float u = d / (1.f + d);
  float idxf = u * (float)M_TAB;
  int i0 = (int)idxf;
  if (i0 > M_TAB - 2) i0 = M_TAB - 2;
  float frac = idxf - (float)i0;
  float f = fmaf(frac, table[i0 + 1] - table[i0], table[i0]);
  float sc = f / fmaxf(d, EPSF);
  atomicAdd(&out[2 * t + 0], sc * dx);
  atomicAdd(&out[2 * t + 1], sc * dy);
}

extern "C" void kernel_launch(void* const* d_in, const int* in_sizes, int n_in,
                              void* d_out, int out_size, void* d_ws,
                              size_t ws_size, hipStream_t stream) {
  const float* x = (const float*)d_in[0];
  const float* v = (const float*)d_in[1];
  const int* src = (const int*)d_in[2];
  const int* dst = (const int*)d_in[3];
  const float* gamma = (const float*)d_in[4];
  const float* W0 = (const float*)d_in[5];
  const float* b0 = (const float*)d_in[6];
  const float* W1 = (const float*)d_in[7];
  const float* b1 = (const float*)d_in[8];
  const float* W2 = (const float*)d_in[9];
  const float* b2 = (const float*)d_in[10];
  const float* W3 = (const float*)d_in[11];
  const float* b3 = (const float*)d_in[12];
  float* out = (float*)d_out;
  float* table = (float*)d_ws;

  int n_out = out_size;           // 200000
  int n_nodes = in_sizes[0] / 2;  // 100000
  int E = in_sizes[2];            // 800000

  const int NB = (E + BCHUNK - 1) / BCHUNK;             // 782
  const int NBUCK = (n_nodes + RANGE_N - 1) / RANGE_N;  // 49
  size_t off_gcnt = 65536;
  size_t off_bin = 131072;
  size_t need = off_bin + (size_t)NBUCK * CAP * 16;

  bool fast = (ws_size >= need) && (n_out == 2 * n_nodes) &&
              (NBUCK <= NBUCK_MAX) && ((size_t)E * 2 <= (size_t)NBUCK * CAP);

  if (fast) {
    int* gcnt = (int*)((char*)d_ws + off_gcnt);
    float4* binData = (float4*)((char*)d_ws + off_bin);
    hipMemsetAsync(gcnt, 0, (size_t)NBUCK * 4, stream);
    hipLaunchKernelGGL(kprod, dim3(NB + M_TAB / TPTS), dim3(256), 0, stream,
                       x, src, dst, W0, b0, W1, b1, W2, b2, W3, b3, binData,
                       gcnt, table, E, NB, NBUCK);
    hipLaunchKernelGGL(kcons, dim3(NBUCK), dim3(1024), 0, stream, binData,
                       gcnt, table, v, gamma, out, n_nodes);
  } else {
    hipLaunchKernelGGL(k2_table, dim3(M_TAB / TPTS), dim3(128), 0, stream, W0,
                       b0, W1, b1, W2, b2, W3, b3, table);
    hipLaunchKernelGGL(k0_init, dim3((n_out + 255) / 256), dim3(256), 0,
                       stream, v, gamma, out, n_out);
    hipLaunchKernelGGL(k3_direct, dim3((E + 255) / 256), dim3(256), 0, stream,
                       x, src, dst, table, out, E);
  }
}

// Round 14
// 58.929 us; speedup vs baseline: 1.7252x; 1.7252x over previous
//
#include <hip/hip_runtime.h>
#include <math.h>

// force = MLP(|dr|) is piecewise-linear in the scalar edge length -> dense
// fp32 table of force(d) parameterized by u = d/(1+d) (data-independent).
//
// Round-14 = round-8 (best, 52us) structure verbatim, with 8-BYTE packed bin
// entries (was 16): word0 = dloc:11 | u:21-bit fixed; word1 = fp16 dy|dx.
// Rules learned r11-r13: producer writes its OWN contiguous region (no
// global reservation, no cross-region scatter); consumer has 392 tiles
// (>=1 block/CU).
//  k3bin (782+256 blocks x 256t): blocks <782 counting-sort 1024 edges by
//      dst-range (64 buckets) into their own 1024-entry region + cnt/off
//      tables; blocks >=782 build the 4096-entry table (16 pts each).
//  k3scat (49 ranges x 8 slices = 392 blocks x 512t): LDS run-prefix +
//      binary search over 98 runs, dense lanes, table lerp, 16 KB LDS
//      accumulate, store partial copy p.
//  k4: out = -gamma*v + sum of 8 partials.

#define M_TAB 4096
#define INV_MTAB (1.0f / 4096.0f)
#define EPSF 1e-12f
#define N_OUT 200000
#define RANGE_N 2048
#define RSHIFT 11
#define NBUCK 64
#define P_SL 8
#define BCHUNK 1024
#define TPTS 16
#define MAXRUN 112
#define U_SCALE 2097152.0f  // 2^21

// Table builder: thread j(<128) = neuron j, TPTS grid points per task.
__device__ __forceinline__ void build_table16(
    int base, int tid, const float* __restrict__ W0,
    const float* __restrict__ b0, const float* __restrict__ W1,
    const float* __restrict__ b1, const float* __restrict__ W2,
    const float* __restrict__ b2, const float* __restrict__ W3,
    const float* __restrict__ b3, float* __restrict__ table,
    float* bufA, float* bufB) {
  const int j = tid;
  if (j < 128) {
    float w = W0[j], b = b0[j];
#pragma unroll
    for (int p = 0; p < TPTS; ++p) {
      float u = (float)(base + p) * INV_MTAB;
      float dd = u / (1.f - u);
      bufA[j * TPTS + p] = fmaxf(fmaf(dd, w, b), 0.f);
    }
  }
  __syncthreads();
  float acc[TPTS];
  if (j < 128) {
    float b = b1[j];
#pragma unroll
    for (int p = 0; p < TPTS; ++p) acc[p] = b;
#pragma unroll 4
    for (int k = 0; k < 128; ++k) {
      float w = W1[k * 128 + j];
#pragma unroll
      for (int q = 0; q < 4; ++q) {
        float4 h = *(const float4*)&bufA[k * TPTS + q * 4];
        acc[q * 4 + 0] = fmaf(h.x, w, acc[q * 4 + 0]);
        acc[q * 4 + 1] = fmaf(h.y, w, acc[q * 4 + 1]);
        acc[q * 4 + 2] = fmaf(h.z, w, acc[q * 4 + 2]);
        acc[q * 4 + 3] = fmaf(h.w, w, acc[q * 4 + 3]);
      }
    }
  }
  __syncthreads();
  if (j < 128) {
#pragma unroll
    for (int p = 0; p < TPTS; ++p) bufB[j * TPTS + p] = fmaxf(acc[p], 0.f);
  }
  __syncthreads();
  if (j < 128) {
    float b = b2[j];
#pragma unroll
    for (int p = 0; p < TPTS; ++p) acc[p] = b;
#pragma unroll 4
    for (int k = 0; k < 128; ++k) {
      float w = W2[k * 128 + j];
#pragma unroll
      for (int q = 0; q < 4; ++q) {
        float4 h = *(const float4*)&bufB[k * TPTS + q * 4];
        acc[q * 4 + 0] = fmaf(h.x, w, acc[q * 4 + 0]);
        acc[q * 4 + 1] = fmaf(h.y, w, acc[q * 4 + 1]);
        acc[q * 4 + 2] = fmaf(h.z, w, acc[q * 4 + 2]);
        acc[q * 4 + 3] = fmaf(h.w, w, acc[q * 4 + 3]);
      }
    }
  }
  __syncthreads();
  if (j < 128) {
    float w3 = W3[j];
#pragma unroll
    for (int p = 0; p < TPTS; ++p)
      bufA[j * TPTS + p] = fmaxf(acc[p], 0.f) * w3;
  }
  __syncthreads();
  for (int s = 64; s > 0; s >>= 1) {
    if (j < s) {
#pragma unroll
      for (int p = 0; p < TPTS; ++p)
        bufA[j * TPTS + p] += bufA[(j + s) * TPTS + p];
    }
    __syncthreads();
  }
  if (j < TPTS) table[base + j] = bufA[j] + b3[0];
}

// k3bin: blocks < NB counting-sort their 1024-edge chunk into their OWN
// region (8-B packed entries); blocks >= NB build the table.
__global__ __launch_bounds__(256) void k3bin(
    const float* __restrict__ x, const int* __restrict__ src,
    const int* __restrict__ dst, const float* __restrict__ W0,
    const float* __restrict__ b0, const float* __restrict__ W1,
    const float* __restrict__ b1, const float* __restrict__ W2,
    const float* __restrict__ b2, const float* __restrict__ W3,
    const float* __restrict__ b3, uint2* __restrict__ binData,
    int* __restrict__ cntTab, int* __restrict__ offTab,
    float* __restrict__ table, int E, int NB) {
  __shared__ float smem[4096];  // table path bufA/bufB (16 KB)
  __shared__ int cntL[NBUCK];
  __shared__ int offL[NBUCK];
  const int tid = threadIdx.x;
  const int bid = blockIdx.x;

  if (bid < NB) {
    if (tid < NBUCK) cntL[tid] = 0;
    __syncthreads();
    const int e0 = bid * BCHUNK + tid * 4;
    int mdst[4], mrank[4];
    float2 xs[4], xt[4];
    float mdx[4], mdy[4], mu[4];
    {
      int msrc[4];
      if (e0 + 3 < E) {
        int4 a = *(const int4*)(src + e0);
        int4 c = *(const int4*)(dst + e0);
        msrc[0] = a.x; msrc[1] = a.y; msrc[2] = a.z; msrc[3] = a.w;
        mdst[0] = c.x; mdst[1] = c.y; mdst[2] = c.z; mdst[3] = c.w;
      } else {
#pragma unroll
        for (int i = 0; i < 4; ++i) {
          bool vv = (e0 + i < E);
          msrc[i] = vv ? src[e0 + i] : 0;
          mdst[i] = vv ? dst[e0 + i] : -1;
        }
      }
      // Issue all 8 gathers before dependent work (ILP).
#pragma unroll
      for (int i = 0; i < 4; ++i) {
        int si = msrc[i], di = mdst[i] < 0 ? 0 : mdst[i];
        xs[i] = ((const float2*)x)[si];
        xt[i] = ((const float2*)x)[di];
      }
    }
#pragma unroll
    for (int i = 0; i < 4; ++i) {
      mdx[i] = xt[i].x - xs[i].x;
      mdy[i] = xt[i].y - xs[i].y;
      float d = sqrtf(fmaf(mdx[i], mdx[i], mdy[i] * mdy[i]));
      mu[i] = d / (1.f + d);
    }
#pragma unroll
    for (int i = 0; i < 4; ++i)
      if (mdst[i] >= 0) mrank[i] = atomicAdd(&cntL[mdst[i] >> RSHIFT], 1);
    __syncthreads();
    if (tid == 0) {
      int s = 0;
#pragma unroll
      for (int k = 0; k < NBUCK; ++k) {
        offL[k] = s;
        s += cntL[k];
      }
    }
    __syncthreads();
    if (tid < NBUCK) {
      cntTab[bid * NBUCK + tid] = cntL[tid];
      offTab[bid * NBUCK + tid] = offL[tid];
    }
    uint2* gout = binData + (size_t)bid * BCHUNK;
#pragma unroll
    for (int i = 0; i < 4; ++i) {
      if (mdst[i] >= 0) {
        int pos = offL[mdst[i] >> RSHIFT] + mrank[i];
        unsigned uq = (unsigned)(mu[i] * U_SCALE);
        unsigned lo = ((unsigned)(mdst[i] & (RANGE_N - 1)) << 21) | uq;
        _Float16 hx = (_Float16)mdx[i];
        _Float16 hy = (_Float16)mdy[i];
        unsigned hxb = *(unsigned short*)&hx;
        unsigned hyb = *(unsigned short*)&hy;
        gout[pos] = make_uint2(lo, (hyb << 16) | hxb);
      }
    }
  } else {
    build_table16((bid - NB) * TPTS, tid, W0, b0, W1, b1, W2, b2, W3, b3,
                  table, smem, smem + 2048);
  }
}

// k3scat: block (r = bid>>3, p = bid&7): consume runs of bin-blocks b%8==p
// for bucket r via LDS run-prefix + binary search; table lerp; 16 KB LDS
// accumulate; plain-store partial copy p.
__global__ __launch_bounds__(512) void k3scat(
    const uint2* __restrict__ binData, const int* __restrict__ cntTab,
    const int* __restrict__ offTab, const float* __restrict__ table,
    float* __restrict__ partial, int NB, int n_nodes) {
  __shared__ float acc[RANGE_N * 2];  // 16 KB
  __shared__ int runStart[MAXRUN];
  __shared__ int pref[MAXRUN + 1];
  const int tid = threadIdx.x;
  const int p = blockIdx.x & (P_SL - 1);
  const int r = blockIdx.x >> 3;

  for (int i = tid; i < RANGE_N * 2; i += 512) acc[i] = 0.f;
  const int nrun = (NB - p + P_SL - 1) / P_SL;
  for (int j = tid; j < nrun; j += 512) {
    int b = p + j * P_SL;
    runStart[j] = b * BCHUNK + offTab[b * NBUCK + r];
    pref[j + 1] = cntTab[b * NBUCK + r];
  }
  __syncthreads();
  if (tid == 0) {
    pref[0] = 0;
    for (int j = 0; j < nrun; ++j) pref[j + 1] += pref[j];
  }
  __syncthreads();

  const int T = pref[nrun];
  for (int g = tid; g < T; g += 512) {
    int lo = 0, hi = nrun;
    while (hi - lo > 1) {
      int mid = (lo + hi) >> 1;
      if (pref[mid] <= g) lo = mid; else hi = mid;
    }
    uint2 ent = binData[(size_t)runStart[lo] + (g - pref[lo])];
    int dloc = (int)(ent.x >> 21);
    float u = (float)(ent.x & 0x1FFFFFu) * (1.f / U_SCALE);
    unsigned short hxb = (unsigned short)(ent.y & 0xFFFFu);
    unsigned short hyb = (unsigned short)(ent.y >> 16);
    float dx = (float)*(_Float16*)&hxb;
    float dy = (float)*(_Float16*)&hyb;
    float idxf = u * (float)M_TAB;
    int i0 = (int)idxf;
    if (i0 > M_TAB - 2) i0 = M_TAB - 2;
    float frac = idxf - (float)i0;
    float f0 = table[i0], f1 = table[i0 + 1];
    float f = fmaf(frac, f1 - f0, f0);
    float d = u / (1.f - u);
    float sc = f / fmaxf(d, EPSF);
    atomicAdd(&acc[dloc * 2], sc * dx);
    atomicAdd(&acc[dloc * 2 + 1], sc * dy);
  }
  __syncthreads();

  const int node0 = r * RANGE_N;
  const int cnt2 = min(RANGE_N, n_nodes - node0);
  float2* po = (float2*)(partial + (size_t)p * N_OUT) + node0;
  const float2* a2 = (const float2*)acc;
  for (int i = tid; i < cnt2; i += 512) po[i] = a2[i];
}

// K4: out = -gamma*v + sum_{p<8} partial[p].
__global__ __launch_bounds__(256) void k4_finish(
    const float4* __restrict__ v4, const float* __restrict__ gamma,
    const float4* __restrict__ part4, float4* __restrict__ out4, int n4) {
  int i = blockIdx.x * blockDim.x + threadIdx.x;
  if (i >= n4) return;
  float g = -gamma[0];
  float4 a = v4[i];
  float4 acc = make_float4(g * a.x, g * a.y, g * a.z, g * a.w);
#pragma unroll
  for (int c = 0; c < P_SL; ++c) {
    float4 p = part4[(size_t)c * (N_OUT / 4) + i];
    acc.x += p.x;
    acc.y += p.y;
    acc.z += p.z;
    acc.w += p.w;
  }
  out4[i] = acc;
}

// ---- Fallback path (tiny d_ws only) ----
__global__ __launch_bounds__(128) void k2_table(
    const float* __restrict__ W0, const float* __restrict__ b0,
    const float* __restrict__ W1, const float* __restrict__ b1,
    const float* __restrict__ W2, const float* __restrict__ b2,
    const float* __restrict__ W3, const float* __restrict__ b3,
    float* __restrict__ table) {
  __shared__ float bufA[2048];
  __shared__ float bufB[2048];
  build_table16(blockIdx.x * TPTS, threadIdx.x, W0, b0, W1, b1, W2, b2, W3,
                b3, table, bufA, bufB);
}

__global__ __launch_bounds__(256) void k0_init(const float* __restrict__ v,
                                               const float* __restrict__ gamma,
                                               float* __restrict__ out,
                                               int n) {
  int i = blockIdx.x * blockDim.x + threadIdx.x;
  if (i < n) out[i] = -gamma[0] * v[i];
}

__global__ __launch_bounds__(256) void k3_direct(
    const float* __restrict__ x, const int* __restrict__ src,
    const int* __restrict__ dst, const float* __restrict__ table,
    float* __restrict__ out, int E) {
  int e = blockIdx.x * blockDim.x + threadIdx.x;
  if (e >= E) return;
  int s = src[e], t = dst[e];
  float2 xs = ((const float2*)x)[s];
  float2 xt = ((const float2*)x)[t];
  float dx = xt.x - xs.x, dy = xt.y - xs.y;
  float d = sqrtf(fmaf(dx, dx, dy * dy));
  float u = d / (1.f + d);
  float idxf = u * (float)M_TAB;
  int i0 = (int)idxf;
  if (i0 > M_TAB - 2) i0 = M_TAB - 2;
  float frac = idxf - (float)i0;
  float f = fmaf(frac, table[i0 + 1] - table[i0], table[i0]);
  float sc = f / fmaxf(d, EPSF);
  atomicAdd(&out[2 * t + 0], sc * dx);
  atomicAdd(&out[2 * t + 1], sc * dy);
}

extern "C" void kernel_launch(void* const* d_in, const int* in_sizes, int n_in,
                              void* d_out, int out_size, void* d_ws,
                              size_t ws_size, hipStream_t stream) {
  const float* x = (const float*)d_in[0];
  const float* v = (const float*)d_in[1];
  const int* src = (const int*)d_in[2];
  const int* dst = (const int*)d_in[3];
  const float* gamma = (const float*)d_in[4];
  const float* W0 = (const float*)d_in[5];
  const float* b0 = (const float*)d_in[6];
  const float* W1 = (const float*)d_in[7];
  const float* b1 = (const float*)d_in[8];
  const float* W2 = (const float*)d_in[9];
  const float* b2 = (const float*)d_in[10];
  const float* W3 = (const float*)d_in[11];
  const float* b3 = (const float*)d_in[12];
  float* out = (float*)d_out;
  float* table = (float*)d_ws;

  int n_out = out_size;           // 200000
  int n_nodes = in_sizes[0] / 2;  // 100000
  int E = in_sizes[2];            // 800000

  const int NB = (E + BCHUNK - 1) / BCHUNK;  // 782
  size_t sz_tab = ((size_t)NB * NBUCK * 4 + 255) & ~(size_t)255;
  size_t off_cnt = 65536;
  size_t off_off = off_cnt + sz_tab;
  size_t off_part = off_off + sz_tab;
  size_t off_bin = off_part + (size_t)P_SL * N_OUT * 4;
  size_t need = off_bin + (size_t)NB * BCHUNK * 8;

  const int NR = (n_nodes + RANGE_N - 1) / RANGE_N;  // 49
  bool fast = (ws_size >= need) && (n_out == N_OUT) && (NR * RANGE_N >= n_nodes) &&
              (NR <= NBUCK) && (n_nodes <= N_OUT / 2) &&
              (NB <= P_SL * MAXRUN) && (NB >= M_TAB / TPTS);

  if (fast) {
    int* cntTab = (int*)((char*)d_ws + off_cnt);
    int* offTab = (int*)((char*)d_ws + off_off);
    float* partial = (float*)((char*)d_ws + off_part);
    uint2* binData = (uint2*)((char*)d_ws + off_bin);
    hipLaunchKernelGGL(k3bin, dim3(NB + M_TAB / TPTS), dim3(256), 0, stream,
                       x, src, dst, W0, b0, W1, b1, W2, b2, W3, b3, binData,
                       cntTab, offTab, table, E, NB);
    hipLaunchKernelGGL(k3scat, dim3(NR * P_SL), dim3(512), 0, stream, binData,
                       cntTab, offTab, table, partial, NB, n_nodes);
    hipLaunchKernelGGL(k4_finish, dim3((N_OUT / 4 + 255) / 256), dim3(256), 0,
                       stream, (const float4*)v, gamma, (const float4*)partial,
                       (float4*)out, N_OUT / 4);
  } else {
    hipLaunchKernelGGL(k2_table, dim3(M_TAB / TPTS), dim3(128), 0, stream, W0,
                       b0, W1, b1, W2, b2, W3, b3, table);
    hipLaunchKernelGGL(k0_init, dim3((n_out + 255) / 256), dim3(256), 0,
                       stream, v, gamma, out, n_out);
    hipLaunchKernelGGL(k3_direct, dim3((E + 255) / 256), dim3(256), 0, stream,
                       x, src, dst, table, out, E);
  }
}

// Round 15
// 42.846 us; speedup vs baseline: 2.3728x; 1.3754x over previous
//
#include <hip/hip_runtime.h>
#include <math.h>

// force = MLP(|dr|) is piecewise-linear in the scalar edge length -> dense
// fp32 table of force(d) parameterized by u = d/(1+d) (data-independent).
//
// Round-15: the producer's 1.6M random x-gathers were the latency wall
// (r14: k3bin 48us at 6% VALU, 17% occ). Producer now touches ONLY src/dst:
// pure streaming counting-sort of packed uint32 {dloc:11|src:17} entries
// into its own region (4 B/entry). Consumer stages x[dst-range] in LDS and
// does all edge math (one x[src] gather per edge, fp32 exact):
//  kbin (512 table blocks FIRST + 391 bin blocks x 256t, 8 edges/thread)
//  kcons (49 ranges x 8 slices = 392 blocks x 512t): LDS x-tile + run
//      prefix + binary search; table lerp; 16 KB LDS acc; store partial p.
//  k4: out = -gamma*v + sum of 8 partials.

#define M_TAB 4096
#define INV_MTAB (1.0f / 4096.0f)
#define EPSF 1e-12f
#define RANGE_N 2048
#define RSHIFT 11
#define NBUCK 64
#define P_SL 8
#define BCHUNK 2048
#define TPTS 8
#define NTABB (M_TAB / TPTS)  // 512 table blocks
#define MAXRUN 64
#define SRC_BITS 17
#define SRC_MASK 0x1FFFFu

// Table builder: thread j(<128) = neuron j, 8 grid points per task.
__device__ __forceinline__ void build_table8(
    int base, int tid, const float* __restrict__ W0,
    const float* __restrict__ b0, const float* __restrict__ W1,
    const float* __restrict__ b1, const float* __restrict__ W2,
    const float* __restrict__ b2, const float* __restrict__ W3,
    const float* __restrict__ b3, float* __restrict__ table,
    float* bufA, float* bufB) {
  const int j = tid;
  if (j < 128) {
    float w = W0[j], b = b0[j];
#pragma unroll
    for (int p = 0; p < TPTS; ++p) {
      float u = (float)(base + p) * INV_MTAB;
      float dd = u / (1.f - u);
      bufA[j * TPTS + p] = fmaxf(fmaf(dd, w, b), 0.f);
    }
  }
  __syncthreads();
  float acc[TPTS];
  if (j < 128) {
    float b = b1[j];
#pragma unroll
    for (int p = 0; p < TPTS; ++p) acc[p] = b;
#pragma unroll 8
    for (int k = 0; k < 128; ++k) {
      float w = W1[k * 128 + j];
      float4 h0 = *(const float4*)&bufA[k * TPTS];
      float4 h1 = *(const float4*)&bufA[k * TPTS + 4];
      acc[0] = fmaf(h0.x, w, acc[0]);
      acc[1] = fmaf(h0.y, w, acc[1]);
      acc[2] = fmaf(h0.z, w, acc[2]);
      acc[3] = fmaf(h0.w, w, acc[3]);
      acc[4] = fmaf(h1.x, w, acc[4]);
      acc[5] = fmaf(h1.y, w, acc[5]);
      acc[6] = fmaf(h1.z, w, acc[6]);
      acc[7] = fmaf(h1.w, w, acc[7]);
    }
  }
  __syncthreads();
  if (j < 128) {
#pragma unroll
    for (int p = 0; p < TPTS; ++p) bufB[j * TPTS + p] = fmaxf(acc[p], 0.f);
  }
  __syncthreads();
  if (j < 128) {
    float b = b2[j];
#pragma unroll
    for (int p = 0; p < TPTS; ++p) acc[p] = b;
#pragma unroll 8
    for (int k = 0; k < 128; ++k) {
      float w = W2[k * 128 + j];
      float4 h0 = *(const float4*)&bufB[k * TPTS];
      float4 h1 = *(const float4*)&bufB[k * TPTS + 4];
      acc[0] = fmaf(h0.x, w, acc[0]);
      acc[1] = fmaf(h0.y, w, acc[1]);
      acc[2] = fmaf(h0.z, w, acc[2]);
      acc[3] = fmaf(h0.w, w, acc[3]);
      acc[4] = fmaf(h1.x, w, acc[4]);
      acc[5] = fmaf(h1.y, w, acc[5]);
      acc[6] = fmaf(h1.z, w, acc[6]);
      acc[7] = fmaf(h1.w, w, acc[7]);
    }
    float w3 = W3[j];
#pragma unroll
    for (int p = 0; p < TPTS; ++p) bufA[j * TPTS + p] = fmaxf(acc[p], 0.f) * w3;
  }
  __syncthreads();
  for (int s = 64; s > 0; s >>= 1) {
    if (j < s) {
#pragma unroll
      for (int p = 0; p < TPTS; ++p)
        bufA[j * TPTS + p] += bufA[(j + s) * TPTS + p];
    }
    __syncthreads();
  }
  if (j < TPTS) table[base + j] = bufA[j] + b3[0];
}

// kbin: blocks < NTABB build table chunk; blocks >= NTABB counting-sort
// their 2048-edge chunk (8/thread) into their OWN region, 4-B entries.
// NO x access, no float math -- pure streaming integer sort.
__global__ __launch_bounds__(256) void kbin(
    const int* __restrict__ src, const int* __restrict__ dst,
    const float* __restrict__ W0, const float* __restrict__ b0,
    const float* __restrict__ W1, const float* __restrict__ b1,
    const float* __restrict__ W2, const float* __restrict__ b2,
    const float* __restrict__ W3, const float* __restrict__ b3,
    unsigned* __restrict__ binData, int* __restrict__ cntTab,
    int* __restrict__ offTab, float* __restrict__ table, int E, int NB) {
  __shared__ float smem[2048];  // table bufA/bufB (8 KB)
  __shared__ int cntL[NBUCK];
  __shared__ int offL[NBUCK];
  const int tid = threadIdx.x;
  const int bid = blockIdx.x;

  if (bid < NTABB) {
    build_table8(bid * TPTS, tid, W0, b0, W1, b1, W2, b2, W3, b3, table,
                 smem, smem + 1024);
    return;
  }
  const int b = bid - NTABB;
  if (tid < NBUCK) cntL[tid] = 0;
  __syncthreads();
  const int e0 = b * BCHUNK + tid * 8;
  int mdst[8], msrc[8], mrank[8];
  if (e0 + 7 < E) {
    int4 c0 = *(const int4*)(dst + e0);
    int4 c1 = *(const int4*)(dst + e0 + 4);
    int4 a0 = *(const int4*)(src + e0);
    int4 a1 = *(const int4*)(src + e0 + 4);
    mdst[0] = c0.x; mdst[1] = c0.y; mdst[2] = c0.z; mdst[3] = c0.w;
    mdst[4] = c1.x; mdst[5] = c1.y; mdst[6] = c1.z; mdst[7] = c1.w;
    msrc[0] = a0.x; msrc[1] = a0.y; msrc[2] = a0.z; msrc[3] = a0.w;
    msrc[4] = a1.x; msrc[5] = a1.y; msrc[6] = a1.z; msrc[7] = a1.w;
  } else {
#pragma unroll
    for (int i = 0; i < 8; ++i) {
      bool vv = (e0 + i < E);
      msrc[i] = vv ? src[e0 + i] : 0;
      mdst[i] = vv ? dst[e0 + i] : -1;
    }
  }
#pragma unroll
  for (int i = 0; i < 8; ++i)
    if (mdst[i] >= 0) mrank[i] = atomicAdd(&cntL[mdst[i] >> RSHIFT], 1);
  __syncthreads();
  if (tid == 0) {
    int s = 0;
#pragma unroll
    for (int k = 0; k < NBUCK; ++k) {
      offL[k] = s;
      s += cntL[k];
    }
  }
  __syncthreads();
  if (tid < NBUCK) {
    cntTab[b * NBUCK + tid] = cntL[tid];
    offTab[b * NBUCK + tid] = offL[tid];
  }
  unsigned* gout = binData + (size_t)b * BCHUNK;
#pragma unroll
  for (int i = 0; i < 8; ++i) {
    if (mdst[i] >= 0) {
      int pos = offL[mdst[i] >> RSHIFT] + mrank[i];
      gout[pos] = ((unsigned)(mdst[i] & (RANGE_N - 1)) << SRC_BITS) |
                  (unsigned)msrc[i];
    }
  }
}

// kcons: block (r = bid>>3, p = bid&7): stage x[range r] in LDS, consume
// runs of bin-blocks b%8==p via run-prefix + binary search, full edge math
// in fp32 (one x[src] gather/edge), accumulate, store partial copy p.
__global__ __launch_bounds__(512) void kcons(
    const unsigned* __restrict__ binData, const int* __restrict__ cntTab,
    const int* __restrict__ offTab, const float* __restrict__ table,
    const float* __restrict__ x, float* __restrict__ partial, int NB,
    int n_nodes, int n_out) {
  __shared__ float acc[RANGE_N * 2];  // 16 KB
  __shared__ float2 xl[RANGE_N];      // 16 KB
  __shared__ int runStart[MAXRUN];
  __shared__ int pref[MAXRUN + 1];
  const int tid = threadIdx.x;
  const int p = blockIdx.x & (P_SL - 1);
  const int r = blockIdx.x >> 3;
  const int node0 = r * RANGE_N;

  for (int i = tid; i < RANGE_N * 2; i += 512) acc[i] = 0.f;
  for (int i = tid; i < RANGE_N; i += 512)
    xl[i] = (node0 + i < n_nodes) ? ((const float2*)x)[node0 + i]
                                  : make_float2(0.f, 0.f);
  const int nrun = (NB - p + P_SL - 1) / P_SL;
  for (int j = tid; j < nrun; j += 512) {
    int b = p + j * P_SL;
    runStart[j] = b * BCHUNK + offTab[b * NBUCK + r];
    pref[j + 1] = cntTab[b * NBUCK + r];
  }
  __syncthreads();
  if (tid == 0) {
    pref[0] = 0;
    for (int j = 0; j < nrun; ++j) pref[j + 1] += pref[j];
  }
  __syncthreads();

  const int T = pref[nrun];
  for (int g = tid; g < T; g += 512) {
    int lo = 0, hi = nrun;
    while (hi - lo > 1) {
      int mid = (lo + hi) >> 1;
      if (pref[mid] <= g) lo = mid; else hi = mid;
    }
    unsigned ent = binData[(size_t)runStart[lo] + (g - pref[lo])];
    int dloc = (int)(ent >> SRC_BITS);
    int s = (int)(ent & SRC_MASK);
    float2 xs = ((const float2*)x)[s];
    float2 xt = xl[dloc];
    float dx = xt.x - xs.x, dy = xt.y - xs.y;
    float d = sqrtf(fmaf(dx, dx, dy * dy));
    float u = d / (1.f + d);
    float idxf = u * (float)M_TAB;
    int i0 = (int)idxf;
    if (i0 > M_TAB - 2) i0 = M_TAB - 2;
    float frac = idxf - (float)i0;
    float f0 = table[i0], f1 = table[i0 + 1];
    float f = fmaf(frac, f1 - f0, f0);
    float sc = f / fmaxf(d, EPSF);
    atomicAdd(&acc[dloc * 2], sc * dx);
    atomicAdd(&acc[dloc * 2 + 1], sc * dy);
  }
  __syncthreads();

  const int cnt2 = min(RANGE_N, n_nodes - node0);
  float2* po = (float2*)(partial + (size_t)p * n_out) + node0;
  const float2* a2 = (const float2*)acc;
  for (int i = tid; i < cnt2; i += 512) po[i] = a2[i];
}

// k4: out = -gamma*v + sum_{p<8} partial[p].
__global__ __launch_bounds__(256) void k4_finish(
    const float4* __restrict__ v4, const float* __restrict__ gamma,
    const float4* __restrict__ part4, float4* __restrict__ out4, int n4) {
  int i = blockIdx.x * blockDim.x + threadIdx.x;
  if (i >= n4) return;
  float g = -gamma[0];
  float4 a = v4[i];
  float4 acc = make_float4(g * a.x, g * a.y, g * a.z, g * a.w);
#pragma unroll
  for (int c = 0; c < P_SL; ++c) {
    float4 p = part4[(size_t)c * n4 + i];
    acc.x += p.x;
    acc.y += p.y;
    acc.z += p.z;
    acc.w += p.w;
  }
  out4[i] = acc;
}

// ---- Fallback path (tiny d_ws only) ----
__global__ __launch_bounds__(128) void k2_table(
    const float* __restrict__ W0, const float* __restrict__ b0,
    const float* __restrict__ W1, const float* __restrict__ b1,
    const float* __restrict__ W2, const float* __restrict__ b2,
    const float* __restrict__ W3, const float* __restrict__ b3,
    float* __restrict__ table) {
  __shared__ float bufA[1024];
  __shared__ float bufB[1024];
  build_table8(blockIdx.x * TPTS, threadIdx.x, W0, b0, W1, b1, W2, b2, W3,
               b3, table, bufA, bufB);
}

__global__ __launch_bounds__(256) void k0_init(const float* __restrict__ v,
                                               const float* __restrict__ gamma,
                                               float* __restrict__ out,
                                               int n) {
  int i = blockIdx.x * blockDim.x + threadIdx.x;
  if (i < n) out[i] = -gamma[0] * v[i];
}

__global__ __launch_bounds__(256) void k3_direct(
    const float* __restrict__ x, const int* __restrict__ src,
    const int* __restrict__ dst, const float* __restrict__ table,
    float* __restrict__ out, int E) {
  int e = blockIdx.x * blockDim.x + threadIdx.x;
  if (e >= E) return;
  int s = src[e], t = dst[e];
  float2 xs = ((const float2*)x)[s];
  float2 xt = ((const float2*)x)[t];
  float dx = xt.x - xs.x, dy = xt.y - xs.y;
  float d = sqrtf(fmaf(dx, dx, dy * dy));
  float u = d / (1.f + d);
  float idxf = u * (float)M_TAB;
  int i0 = (int)idxf;
  if (i0 > M_TAB - 2) i0 = M_TAB - 2;
  float frac = idxf - (float)i0;
  float f = fmaf(frac, table[i0 + 1] - table[i0], table[i0]);
  float sc = f / fmaxf(d, EPSF);
  atomicAdd(&out[2 * t + 0], sc * dx);
  atomicAdd(&out[2 * t + 1], sc * dy);
}

extern "C" void kernel_launch(void* const* d_in, const int* in_sizes, int n_in,
                              void* d_out, int out_size, void* d_ws,
                              size_t ws_size, hipStream_t stream) {
  const float* x = (const float*)d_in[0];
  const float* v = (const float*)d_in[1];
  const int* src = (const int*)d_in[2];
  const int* dst = (const int*)d_in[3];
  const float* gamma = (const float*)d_in[4];
  const float* W0 = (const float*)d_in[5];
  const float* b0 = (const float*)d_in[6];
  const float* W1 = (const float*)d_in[7];
  const float* b1 = (const float*)d_in[8];
  const float* W2 = (const float*)d_in[9];
  const float* b2 = (const float*)d_in[10];
  const float* W3 = (const float*)d_in[11];
  const float* b3 = (const float*)d_in[12];
  float* out = (float*)d_out;
  float* table = (float*)d_ws;

  int n_out = out_size;           // 200000
  int n_nodes = in_sizes[0] / 2;  // 100000
  int E = in_sizes[2];            // 800000

  const int NB = (E + BCHUNK - 1) / BCHUNK;          // 391
  const int NR = (n_nodes + RANGE_N - 1) / RANGE_N;  // 49
  size_t sz_tab = ((size_t)NB * NBUCK * 4 + 255) & ~(size_t)255;
  size_t off_cnt = 65536;
  size_t off_off = off_cnt + sz_tab;
  size_t off_part = off_off + sz_tab;
  size_t off_bin = off_part + (size_t)P_SL * n_out * 4;
  size_t need = off_bin + (size_t)NB * BCHUNK * 4;

  bool fast = (ws_size >= need) && (n_out == 2 * n_nodes) &&
              (n_nodes <= (1 << SRC_BITS)) && (NR <= NBUCK) &&
              (NB <= P_SL * MAXRUN) && ((n_out & 3) == 0);

  if (fast) {
    int* cntTab = (int*)((char*)d_ws + off_cnt);
    int* offTab = (int*)((char*)d_ws + off_off);
    float* partial = (float*)((char*)d_ws + off_part);
    unsigned* binData = (unsigned*)((char*)d_ws + off_bin);
    hipLaunchKernelGGL(kbin, dim3(NTABB + NB), dim3(256), 0, stream, src, dst,
                       W0, b0, W1, b1, W2, b2, W3, b3, binData, cntTab,
                       offTab, table, E, NB);
    hipLaunchKernelGGL(kcons, dim3(NR * P_SL), dim3(512), 0, stream, binData,
                       cntTab, offTab, table, x, partial, NB, n_nodes, n_out);
    hipLaunchKernelGGL(k4_finish, dim3((n_out / 4 + 255) / 256), dim3(256), 0,
                       stream, (const float4*)v, gamma, (const float4*)partial,
                       (float4*)out, n_out / 4);
  } else {
    hipLaunchKernelGGL(k2_table, dim3(NTABB), dim3(128), 0, stream, W0, b0,
                       W1, b1, W2, b2, W3, b3, table);
    hipLaunchKernelGGL(k0_init, dim3((n_out + 255) / 256), dim3(256), 0,
                       stream, v, gamma, out, n_out);
    hipLaunchKernelGGL(k3_direct, dim3((E + 255) / 256), dim3(256), 0, stream,
                       x, src, dst, table, out, E);
  }
}